// Round 1
// baseline (290.229 us; speedup 1.0000x reference)
//
#include <hip/hip_runtime.h>
#include <math.h>

// GSSIM loss, fully fused tile kernel.
// pred/target: f32 [B,1,H,W], min/max: f32 [B]. Output: 1 f32 scalar.
// Pipeline per 32x32 output tile:
//   1) stage normalized p,t over 40x40 halo region (zero-padded) in LDS
//   2) Sobel grad magnitude over 38x38 region (zero outside image) in LDS
//   3) horizontal 7-tap sums of {p,t,gp,gt,gp2,gt2,gpgt} -> LDS
//   4) vertical 7-tap sums + SSIM math + block reduction -> partial[block]
// Second kernel: deterministic double-precision reduce -> 1 - mean.

#define EPS_F 1e-6f
#define C1_F 1e-4f
#define C2_F 9e-4f

constexpr int TH = 32, TW = 32;
constexpr int RIN = 4;            // 1 (sobel) + 3 (box)
constexpr int INH = TH + 2 * RIN; // 40
constexpr int INW = TW + 2 * RIN; // 40
constexpr int GH = TH + 6;        // 38 (grad/box region, offset -3)
constexpr int GW = TW + 6;        // 38
constexpr int NTHREADS = 256;

__global__ __launch_bounds__(NTHREADS, 2)
void gssim_tile(const float* __restrict__ pred, const float* __restrict__ target,
                const float* __restrict__ mn_arr, const float* __restrict__ mx_arr,
                float* __restrict__ partial, int H, int W) {
    __shared__ float sp[INH][INW + 1];   // normalized p (zero outside image)
    __shared__ float st[INH][INW + 1];   // normalized t
    __shared__ float sgp[GH][GW + 1];    // grad mag of p (zero outside image)
    __shared__ float sgt[GH][GW + 1];
    __shared__ float hs[7][GH][TW];      // horizontal 7-tap sums of 7 stats
    __shared__ float red[4];

    const int b   = blockIdx.z;
    const int gy0 = blockIdx.y * TH;
    const int gx0 = blockIdx.x * TW;
    const int tid = threadIdx.x;

    const float mn     = mn_arr[b];
    const float dr     = fmaxf(mx_arr[b] - mn, EPS_F);
    const float inv_dr = 1.0f / dr;
    const size_t base  = (size_t)b * (size_t)H * (size_t)W;

    // ---- Phase 1: load + normalize, zero-padded halo (offset -4) ----
    for (int i = tid; i < INH * INW; i += NTHREADS) {
        int y = i / INW, x = i - y * INW;
        int gy = gy0 - RIN + y, gx = gx0 - RIN + x;
        float pv = 0.0f, tv = 0.0f;
        if (gy >= 0 && gy < H && gx >= 0 && gx < W) {
            size_t idx = base + (size_t)gy * W + (size_t)gx;
            pv = (pred[idx] - mn) * inv_dr;
            tv = (target[idx] - mn) * inv_dr;
        }
        sp[y][x] = pv;
        st[y][x] = tv;
    }
    __syncthreads();

    // ---- Phase 2: Sobel grad magnitude over grad region (offset -3) ----
    // gp = 0 for positions outside the image (box zero-pads gp itself);
    // in-image border positions use zero-padded p (conv zero padding).
    for (int i = tid; i < GH * GW; i += NTHREADS) {
        int y = i / GW, x = i - y * GW;
        int gy = gy0 - 3 + y, gx = gx0 - 3 + x;
        float gpv = 0.0f, gtv = 0.0f;
        if (gy >= 0 && gy < H && gx >= 0 && gx < W) {
            int c = y + 1, d = x + 1; // center in sp coords (offset -4 vs -3)
            {
                float a00 = sp[c - 1][d - 1], a01 = sp[c - 1][d], a02 = sp[c - 1][d + 1];
                float a10 = sp[c][d - 1],                         a12 = sp[c][d + 1];
                float a20 = sp[c + 1][d - 1], a21 = sp[c + 1][d], a22 = sp[c + 1][d + 1];
                float gxv = (a02 - a00) + 2.0f * (a12 - a10) + (a22 - a20);
                float gyv = (a20 - a00) + 2.0f * (a21 - a01) + (a22 - a02);
                gpv = sqrtf(gxv * gxv + gyv * gyv + EPS_F);
            }
            {
                float a00 = st[c - 1][d - 1], a01 = st[c - 1][d], a02 = st[c - 1][d + 1];
                float a10 = st[c][d - 1],                         a12 = st[c][d + 1];
                float a20 = st[c + 1][d - 1], a21 = st[c + 1][d], a22 = st[c + 1][d + 1];
                float gxv = (a02 - a00) + 2.0f * (a12 - a10) + (a22 - a20);
                float gyv = (a20 - a00) + 2.0f * (a21 - a01) + (a22 - a02);
                gtv = sqrtf(gxv * gxv + gyv * gyv + EPS_F);
            }
        }
        sgp[y][x] = gpv;
        sgt[y][x] = gtv;
    }
    __syncthreads();

    // ---- Phase 3: horizontal 7-tap sums at (grad row y, output col ox) ----
    for (int i = tid; i < GH * TW; i += NTHREADS) {
        int y = i >> 5, ox = i & 31; // TW == 32
        float s_p = 0.f, s_t = 0.f, s_gp = 0.f, s_gt = 0.f;
        float s_gp2 = 0.f, s_gt2 = 0.f, s_gpgt = 0.f;
#pragma unroll
        for (int dx = 0; dx < 7; ++dx) {
            int c = ox + dx; // grad col
            float pv = sp[y + 1][c + 1];
            float tv = st[y + 1][c + 1];
            float gp = sgp[y][c];
            float gt = sgt[y][c];
            s_p += pv; s_t += tv; s_gp += gp; s_gt += gt;
            s_gp2 += gp * gp; s_gt2 += gt * gt; s_gpgt += gp * gt;
        }
        hs[0][y][ox] = s_p;   hs[1][y][ox] = s_t;
        hs[2][y][ox] = s_gp;  hs[3][y][ox] = s_gt;
        hs[4][y][ox] = s_gp2; hs[5][y][ox] = s_gt2;
        hs[6][y][ox] = s_gpgt;
    }
    __syncthreads();

    // ---- Phase 4: vertical 7-tap sums + SSIM math + accumulate ----
    const float inv49 = 1.0f / 49.0f;
    float acc = 0.0f;
#pragma unroll
    for (int k = 0; k < 4; ++k) {
        int oy = (tid >> 5) + 8 * k; // 0..31
        int ox = tid & 31;
        float v0 = 0.f, v1 = 0.f, v2 = 0.f, v3 = 0.f, v4 = 0.f, v5 = 0.f, v6 = 0.f;
#pragma unroll
        for (int dy = 0; dy < 7; ++dy) {
            int r = oy + dy;
            v0 += hs[0][r][ox];
            v1 += hs[1][r][ox];
            v2 += hs[2][r][ox];
            v3 += hs[3][r][ox];
            v4 += hs[4][r][ox];
            v5 += hs[5][r][ox];
            v6 += hs[6][r][ox];
        }
        float mu_p  = v0 * inv49, mu_t  = v1 * inv49;
        float mu_gp = v2 * inv49, mu_gt = v3 * inv49;
        float sig_p = v4 * inv49 - mu_gp * mu_gp;
        float sig_t = v5 * inv49 - mu_gt * mu_gt;
        float sig_x = v6 * inv49 - mu_gp * mu_gt;
        float lum = (2.0f * mu_p * mu_t + C1_F) / (mu_p * mu_p + mu_t * mu_t + C1_F);
        float cs  = (2.0f * sig_x + C2_F) / (sig_p + sig_t + C2_F);
        acc += lum * cs;
    }

    // ---- Block reduction (deterministic) ----
#pragma unroll
    for (int off = 32; off > 0; off >>= 1) acc += __shfl_down(acc, off, 64);
    int wave = tid >> 6, lane = tid & 63;
    if (lane == 0) red[wave] = acc;
    __syncthreads();
    if (tid == 0) {
        float s = red[0] + red[1] + red[2] + red[3];
        partial[((size_t)blockIdx.z * gridDim.y + blockIdx.y) * gridDim.x + blockIdx.x] = s;
    }
}

__global__ __launch_bounds__(256)
void gssim_final(const float* __restrict__ partial, int n,
                 float* __restrict__ out, double inv_count) {
    __shared__ double sred[256];
    double acc = 0.0;
    for (int i = threadIdx.x; i < n; i += 256) acc += (double)partial[i];
    sred[threadIdx.x] = acc;
    __syncthreads();
    for (int s = 128; s > 0; s >>= 1) {
        if ((int)threadIdx.x < s) sred[threadIdx.x] += sred[threadIdx.x + s];
        __syncthreads();
    }
    if (threadIdx.x == 0) out[0] = (float)(1.0 - sred[0] * inv_count);
}

extern "C" void kernel_launch(void* const* d_in, const int* in_sizes, int n_in,
                              void* d_out, int out_size, void* d_ws, size_t ws_size,
                              hipStream_t stream) {
    const float* pred   = (const float*)d_in[0];
    const float* target = (const float*)d_in[1];
    const float* mn     = (const float*)d_in[2];
    const float* mx     = (const float*)d_in[3];
    float* out = (float*)d_out;

    const int B = in_sizes[2];      // 64
    const int H = 512, W = 512;     // fixed problem shape (in_sizes[0] = B*H*W)

    float* partial = (float*)d_ws;  // (W/TW)*(H/TH)*B floats = 64 KB

    dim3 grid(W / TW, H / TH, B);   // 16 x 16 x 64
    gssim_tile<<<grid, NTHREADS, 0, stream>>>(pred, target, mn, mx, partial, H, W);

    const int nblocks = (W / TW) * (H / TH) * B;
    const double inv_count = 1.0 / ((double)B * (double)H * (double)W);
    gssim_final<<<1, 256, 0, stream>>>(partial, nblocks, out, inv_count);
}

// Round 3
// 110.041 us; speedup vs baseline: 2.6375x; 2.6375x over previous
//
#include <hip/hip_runtime.h>
#include <hip/hip_fp16.h>
#include <math.h>

// GSSIM loss, fused tile kernel, f16-packed (p,t)/(gp,gt) intermediates.
// Per 32x32 output tile:
//   P1: load+normalize (p,t) -> half2 spt[40][44]          (zero-padded halo)
//   P2: packed Sobel grad mag -> half2 sg[38][40]          (zero outside image)
//   P3: horizontal sliding 7-sums of 4 packed stats -> hs*[38][32]
//   P4: vertical packed 7-sums + SSIM (f32) + block reduce -> partial[block]
// Kernel 2: deterministic f64 reduce -> 1 - mean.

constexpr int NT = 256;
constexpr float EPS_F = 1e-6f;
constexpr float C1S = 2401.0f * 0.0001f;  // C1 * 49^2
constexpr float C2S = 2401.0f * 0.0009f;  // C2 * 49^2

union U4 { uint4 u; __half2 h[4]; };

// swap low/high halves of a half2 (single v_alignbit_b32)
__device__ __forceinline__ __half2 h2swap(__half2 x) {
    unsigned u = __builtin_bit_cast(unsigned, x);
    u = (u >> 16) | (u << 16);
    return __builtin_bit_cast(__half2, u);
}

__global__ __launch_bounds__(NT, 4)
void gssim_tile(const float* __restrict__ pred, const float* __restrict__ target,
                const float* __restrict__ mn_arr, const float* __restrict__ mx_arr,
                float* __restrict__ partial, int H, int W) {
    __shared__ alignas(16) __half2 spt[40][44];   // (p,t), image rows gy0-4.., cols gx0-4..
    __shared__ alignas(16) __half2 sg[38][40];    // (gp,gt), grad idx k=row-(gy0-3), j=col-(gx0-3)
    __shared__ alignas(16) __half2 hspt[38][32];  // H-sums (Σp,Σt)
    __shared__ alignas(16) __half2 hsg [38][32];  // (Σgp,Σgt)
    __shared__ alignas(16) __half2 hsgg[38][32];  // (Σgp²,Σgt²)
    __shared__ alignas(16) __half2 hsgx[38][32];  // (Σgp·gt, dup)
    __shared__ float red[4];

    const int b   = blockIdx.z;
    const int gy0 = blockIdx.y * 32;
    const int gx0 = blockIdx.x * 32;
    const int tid = threadIdx.x;

    const float mn     = mn_arr[b];
    const float inv_dr = 1.0f / fmaxf(mx_arr[b] - mn, EPS_F);
    const size_t base  = (size_t)b * (size_t)H * (size_t)W;

    // ---- P1: load + normalize + pack ----
    for (int i = tid; i < 400; i += NT) {
        int y = i / 10, g = i - y * 10;   // y in [0,40), g in [0,10)
        int gy = gy0 - 4 + y;
        int gx = gx0 - 4 + 4 * g;
        U4 w;
        if (gy >= 0 && gy < H && gx >= 0 && gx + 4 <= W) {
            const float4 pv = *reinterpret_cast<const float4*>(pred   + base + (size_t)gy * W + gx);
            const float4 tv = *reinterpret_cast<const float4*>(target + base + (size_t)gy * W + gx);
            w.h[0] = __floats2half2_rn((pv.x - mn) * inv_dr, (tv.x - mn) * inv_dr);
            w.h[1] = __floats2half2_rn((pv.y - mn) * inv_dr, (tv.y - mn) * inv_dr);
            w.h[2] = __floats2half2_rn((pv.z - mn) * inv_dr, (tv.z - mn) * inv_dr);
            w.h[3] = __floats2half2_rn((pv.w - mn) * inv_dr, (tv.w - mn) * inv_dr);
        } else {
#pragma unroll
            for (int c = 0; c < 4; ++c) {
                int x = gx + c;
                bool ok = (gy >= 0 && gy < H && x >= 0 && x < W);
                float pv = 0.0f, tv = 0.0f;
                if (ok) {
                    size_t idx = base + (size_t)gy * W + (size_t)x;
                    pv = (pred[idx] - mn) * inv_dr;
                    tv = (target[idx] - mn) * inv_dr;
                }
                w.h[c] = __floats2half2_rn(pv, tv);
            }
        }
        *reinterpret_cast<uint4*>(&spt[y][4 * g]) = w.u;
    }
    __syncthreads();

    // ---- P2: packed Sobel grad magnitude ----
    const __half2 two2  = __float2half2_rn(2.0f);
    const __half2 eps2  = __float2half2_rn(1e-6f);
    const __half2 zero2 = __float2half2_rn(0.0f);
    for (int i = tid; i < 380; i += NT) {
        int k = i / 10, g = i - k * 10;   // k in [0,38), g in [0,10)
        int j0 = 4 * g;
        U4 w; w.h[0] = zero2; w.h[1] = zero2; w.h[2] = zero2; w.h[3] = zero2;
        int gr = gy0 + k - 3;             // image row of this grad row
        if (gr >= 0 && gr < H) {
            __half2 a[3][6];
#pragma unroll
            for (int r = 0; r < 3; ++r) {
                U4 v; v.u = *reinterpret_cast<const uint4*>(&spt[k + r][j0]);
                a[r][0] = v.h[0]; a[r][1] = v.h[1]; a[r][2] = v.h[2]; a[r][3] = v.h[3];
                uint2 v2 = *reinterpret_cast<const uint2*>(&spt[k + r][j0 + 4]);
                a[r][4] = __builtin_bit_cast(__half2, v2.x);
                a[r][5] = __builtin_bit_cast(__half2, v2.y);
            }
#pragma unroll
            for (int c = 0; c < 4; ++c) {
                __half2 gxh = __hsub2(a[0][c + 2], a[0][c]);
                gxh = __hfma2(two2, __hsub2(a[1][c + 2], a[1][c]), gxh);
                gxh = __hadd2(gxh, __hsub2(a[2][c + 2], a[2][c]));
                __half2 gyh = __hsub2(a[2][c], a[0][c]);
                gyh = __hfma2(two2, __hsub2(a[2][c + 1], a[0][c + 1]), gyh);
                gyh = __hadd2(gyh, __hsub2(a[2][c + 2], a[0][c + 2]));
                __half2 m2 = __hfma2(gxh, gxh, __hfma2(gyh, gyh, eps2));
                __half2 mag = h2sqrt(m2);
                int gc = gx0 + j0 + c - 3;   // image col of this grad col
                w.h[c] = (gc >= 0 && gc < W) ? mag : zero2;
            }
        }
        *reinterpret_cast<uint4*>(&sg[k][j0]) = w.u;
    }
    __syncthreads();

    // ---- P3: horizontal sliding 7-sums (4 output cols per task) ----
    for (int i = tid; i < 304; i += NT) {
        int k  = i >> 3;          // grad row 0..37
        int c0 = (i & 7) * 4;     // output col base 0..28
        __half2 ptv[12], sgv[12];
#pragma unroll
        for (int q = 0; q < 3; ++q) {
            U4 v; v.u = *reinterpret_cast<const uint4*>(&spt[k + 1][c0 + 4 * q]);
            ptv[4 * q] = v.h[0]; ptv[4 * q + 1] = v.h[1]; ptv[4 * q + 2] = v.h[2]; ptv[4 * q + 3] = v.h[3];
            U4 u; u.u = *reinterpret_cast<const uint4*>(&sg[k][c0 + 4 * q]);
            sgv[4 * q] = u.h[0]; sgv[4 * q + 1] = u.h[1]; sgv[4 * q + 2] = u.h[2]; sgv[4 * q + 3] = u.h[3];
        }
        __half2 gg[10], gx2[10];
#pragma unroll
        for (int q = 0; q < 10; ++q) {
            gg[q]  = __hmul2(sgv[q], sgv[q]);
            gx2[q] = __hmul2(sgv[q], h2swap(sgv[q]));
        }
        // init windows (output col c0): p,t taps are ptv[1..7]; grad taps idx 0..6
        __half2 Hpt = ptv[1], Hg = sgv[0], Hgg = gg[0], Hgx = gx2[0];
#pragma unroll
        for (int q = 1; q < 7; ++q) {
            Hpt = __hadd2(Hpt, ptv[q + 1]);
            Hg  = __hadd2(Hg,  sgv[q]);
            Hgg = __hadd2(Hgg, gg[q]);
            Hgx = __hadd2(Hgx, gx2[q]);
        }
        U4 opt, og, ogg, ogx;
        opt.h[0] = Hpt; og.h[0] = Hg; ogg.h[0] = Hgg; ogx.h[0] = Hgx;
#pragma unroll
        for (int m = 1; m < 4; ++m) {
            Hpt = __hadd2(__hsub2(Hpt, ptv[m]),      ptv[m + 7]);
            Hg  = __hadd2(__hsub2(Hg,  sgv[m - 1]),  sgv[m + 6]);
            Hgg = __hadd2(__hsub2(Hgg, gg[m - 1]),   gg[m + 6]);
            Hgx = __hadd2(__hsub2(Hgx, gx2[m - 1]),  gx2[m + 6]);
            opt.h[m] = Hpt; og.h[m] = Hg; ogg.h[m] = Hgg; ogx.h[m] = Hgx;
        }
        *reinterpret_cast<uint4*>(&hspt[k][c0]) = opt.u;
        *reinterpret_cast<uint4*>(&hsg [k][c0]) = og.u;
        *reinterpret_cast<uint4*>(&hsgg[k][c0]) = ogg.u;
        *reinterpret_cast<uint4*>(&hsgx[k][c0]) = ogx.u;
    }
    __syncthreads();

    // ---- P4: vertical packed 7-sums + SSIM ----
    float accl = 0.0f;
    {
        int oy = tid >> 3;
        int c0 = (tid & 7) * 4;
        U4 apt, ag, agg, agx;
        apt.u = *reinterpret_cast<const uint4*>(&hspt[oy][c0]);
        ag.u  = *reinterpret_cast<const uint4*>(&hsg [oy][c0]);
        agg.u = *reinterpret_cast<const uint4*>(&hsgg[oy][c0]);
        agx.u = *reinterpret_cast<const uint4*>(&hsgx[oy][c0]);
#pragma unroll
        for (int r = 1; r < 7; ++r) {
            U4 v;
            v.u = *reinterpret_cast<const uint4*>(&hspt[oy + r][c0]);
#pragma unroll
            for (int m = 0; m < 4; ++m) apt.h[m] = __hadd2(apt.h[m], v.h[m]);
            v.u = *reinterpret_cast<const uint4*>(&hsg[oy + r][c0]);
#pragma unroll
            for (int m = 0; m < 4; ++m) ag.h[m] = __hadd2(ag.h[m], v.h[m]);
            v.u = *reinterpret_cast<const uint4*>(&hsgg[oy + r][c0]);
#pragma unroll
            for (int m = 0; m < 4; ++m) agg.h[m] = __hadd2(agg.h[m], v.h[m]);
            v.u = *reinterpret_cast<const uint4*>(&hsgx[oy + r][c0]);
#pragma unroll
            for (int m = 0; m < 4; ++m) agx.h[m] = __hadd2(agx.h[m], v.h[m]);
        }
#pragma unroll
        for (int m = 0; m < 4; ++m) {
            float2 vpt = __half22float2(apt.h[m]);
            float2 vg  = __half22float2(ag.h[m]);
            float2 vgg = __half22float2(agg.h[m]);
            float  vgx = __low2float(agx.h[m]);
            float lum_n = 2.0f * vpt.x * vpt.y + C1S;
            float lum_d = vpt.x * vpt.x + vpt.y * vpt.y + C1S;
            float cs_n  = 2.0f * (49.0f * vgx - vg.x * vg.y) + C2S;
            float cs_d  = 49.0f * (vgg.x + vgg.y) - vg.x * vg.x - vg.y * vg.y + C2S;
            accl += lum_n * cs_n * __builtin_amdgcn_rcpf(lum_d) * __builtin_amdgcn_rcpf(cs_d);
        }
    }

    // ---- block reduction (deterministic) ----
#pragma unroll
    for (int off = 32; off > 0; off >>= 1) accl += __shfl_down(accl, off, 64);
    if ((tid & 63) == 0) red[tid >> 6] = accl;
    __syncthreads();
    if (tid == 0) {
        partial[((size_t)blockIdx.z * gridDim.y + blockIdx.y) * gridDim.x + blockIdx.x]
            = red[0] + red[1] + red[2] + red[3];
    }
}

__global__ __launch_bounds__(256)
void gssim_final(const float* __restrict__ partial, int n,
                 float* __restrict__ out, double inv_count) {
    __shared__ double sred[256];
    double acc = 0.0;
    for (int i = threadIdx.x; i < n; i += 256) acc += (double)partial[i];
    sred[threadIdx.x] = acc;
    __syncthreads();
    for (int s = 128; s > 0; s >>= 1) {
        if ((int)threadIdx.x < s) sred[threadIdx.x] += sred[threadIdx.x + s];
        __syncthreads();
    }
    if (threadIdx.x == 0) out[0] = (float)(1.0 - sred[0] * inv_count);
}

extern "C" void kernel_launch(void* const* d_in, const int* in_sizes, int n_in,
                              void* d_out, int out_size, void* d_ws, size_t ws_size,
                              hipStream_t stream) {
    const float* pred   = (const float*)d_in[0];
    const float* target = (const float*)d_in[1];
    const float* mn     = (const float*)d_in[2];
    const float* mx     = (const float*)d_in[3];
    float* out = (float*)d_out;

    const int B = in_sizes[2];      // 64
    const int H = 512, W = 512;

    float* partial = (float*)d_ws;

    dim3 grid(W / 32, H / 32, B);   // 16 x 16 x 64
    gssim_tile<<<grid, NT, 0, stream>>>(pred, target, mn, mx, partial, H, W);

    const int nblocks = (W / 32) * (H / 32) * B;
    const double inv_count = 1.0 / ((double)B * (double)H * (double)W);
    gssim_final<<<1, 256, 0, stream>>>(partial, nblocks, out, inv_count);
}

// Round 4
// 109.584 us; speedup vs baseline: 2.6485x; 1.0042x over previous
//
#include <hip/hip_runtime.h>
#include <hip/hip_fp16.h>
#include <math.h>

// GSSIM loss, fused tile kernel, f16-packed, vertical-sliding P4.
// Per 32x32 output tile:
//   P1: load+normalize (p,t) -> half2 spt[40][44]          (zero-padded halo)
//   P2: packed Sobel grad mag -> half2 sg[38][40]          (zero outside image)
//   P3: horizontal sliding 7-sums -> interleaved hsAll[col][row][4]
//   P4: per-column vertical sliding 7-sums + SSIM + block reduce
// Kernel 2: deterministic f64 reduce -> 1 - mean.

constexpr int NT = 256;
constexpr float EPS_F = 1e-6f;
constexpr float C1S = 2401.0f * 0.0001f;  // C1 * 49^2
constexpr float C2S = 2401.0f * 0.0009f;  // C2 * 49^2

union U4 { uint4 u; __half2 h[4]; };

// swap low/high halves of a half2 (single v_alignbit_b32)
__device__ __forceinline__ __half2 h2swap(__half2 x) {
    unsigned u = __builtin_bit_cast(unsigned, x);
    u = (u >> 16) | (u << 16);
    return __builtin_bit_cast(__half2, u);
}

__device__ __forceinline__ float ssim_px(__half2 apt, __half2 ag, __half2 agg, __half2 agx) {
    float2 vpt = __half22float2(apt);
    float2 vg  = __half22float2(ag);
    float2 vgg = __half22float2(agg);
    float  vgx = __low2float(agx);
    float lum_n = 2.0f * vpt.x * vpt.y + C1S;
    float lum_d = vpt.x * vpt.x + vpt.y * vpt.y + C1S;
    float cs_n  = 2.0f * (49.0f * vgx - vg.x * vg.y) + C2S;
    float cs_d  = 49.0f * (vgg.x + vgg.y) - vg.x * vg.x - vg.y * vg.y + C2S;
    return lum_n * cs_n * __builtin_amdgcn_rcpf(lum_d) * __builtin_amdgcn_rcpf(cs_d);
}

__global__ __launch_bounds__(NT, 4)
void gssim_tile(const float* __restrict__ pred, const float* __restrict__ target,
                const float* __restrict__ mn_arr, const float* __restrict__ mx_arr,
                float* __restrict__ partial, int H, int W) {
    __shared__ alignas(16) __half2 spt[40][44];    // (p,t)
    __shared__ alignas(16) __half2 sg[38][40];     // (gp,gt)
    __shared__ alignas(16) __half2 hsAll[32][39][4]; // [col][grad row][stat], pad 39
    __shared__ float red[4];

    const int b   = blockIdx.z;
    const int gy0 = blockIdx.y * 32;
    const int gx0 = blockIdx.x * 32;
    const int tid = threadIdx.x;

    const float mn     = mn_arr[b];
    const float inv_dr = 1.0f / fmaxf(mx_arr[b] - mn, EPS_F);
    const size_t base  = (size_t)b * (size_t)H * (size_t)W;

    // ---- P1: load + normalize + pack ----
    for (int i = tid; i < 400; i += NT) {
        int y = i / 10, g = i - y * 10;
        int gy = gy0 - 4 + y;
        int gx = gx0 - 4 + 4 * g;
        U4 w;
        if (gy >= 0 && gy < H && gx >= 0 && gx + 4 <= W) {
            const float4 pv = *reinterpret_cast<const float4*>(pred   + base + (size_t)gy * W + gx);
            const float4 tv = *reinterpret_cast<const float4*>(target + base + (size_t)gy * W + gx);
            w.h[0] = __floats2half2_rn((pv.x - mn) * inv_dr, (tv.x - mn) * inv_dr);
            w.h[1] = __floats2half2_rn((pv.y - mn) * inv_dr, (tv.y - mn) * inv_dr);
            w.h[2] = __floats2half2_rn((pv.z - mn) * inv_dr, (tv.z - mn) * inv_dr);
            w.h[3] = __floats2half2_rn((pv.w - mn) * inv_dr, (tv.w - mn) * inv_dr);
        } else {
#pragma unroll
            for (int c = 0; c < 4; ++c) {
                int x = gx + c;
                bool ok = (gy >= 0 && gy < H && x >= 0 && x < W);
                float pv = 0.0f, tv = 0.0f;
                if (ok) {
                    size_t idx = base + (size_t)gy * W + (size_t)x;
                    pv = (pred[idx] - mn) * inv_dr;
                    tv = (target[idx] - mn) * inv_dr;
                }
                w.h[c] = __floats2half2_rn(pv, tv);
            }
        }
        *reinterpret_cast<uint4*>(&spt[y][4 * g]) = w.u;
    }
    __syncthreads();

    // ---- P2: packed Sobel grad magnitude ----
    const __half2 two2  = __float2half2_rn(2.0f);
    const __half2 eps2  = __float2half2_rn(1e-6f);
    const __half2 zero2 = __float2half2_rn(0.0f);
    for (int i = tid; i < 380; i += NT) {
        int k = i / 10, g = i - k * 10;
        int j0 = 4 * g;
        U4 w; w.h[0] = zero2; w.h[1] = zero2; w.h[2] = zero2; w.h[3] = zero2;
        int gr = gy0 + k - 3;
        if (gr >= 0 && gr < H) {
            __half2 a[3][6];
#pragma unroll
            for (int r = 0; r < 3; ++r) {
                U4 v; v.u = *reinterpret_cast<const uint4*>(&spt[k + r][j0]);
                a[r][0] = v.h[0]; a[r][1] = v.h[1]; a[r][2] = v.h[2]; a[r][3] = v.h[3];
                uint2 v2 = *reinterpret_cast<const uint2*>(&spt[k + r][j0 + 4]);
                a[r][4] = __builtin_bit_cast(__half2, v2.x);
                a[r][5] = __builtin_bit_cast(__half2, v2.y);
            }
#pragma unroll
            for (int c = 0; c < 4; ++c) {
                __half2 gxh = __hsub2(a[0][c + 2], a[0][c]);
                gxh = __hfma2(two2, __hsub2(a[1][c + 2], a[1][c]), gxh);
                gxh = __hadd2(gxh, __hsub2(a[2][c + 2], a[2][c]));
                __half2 gyh = __hsub2(a[2][c], a[0][c]);
                gyh = __hfma2(two2, __hsub2(a[2][c + 1], a[0][c + 1]), gyh);
                gyh = __hadd2(gyh, __hsub2(a[2][c + 2], a[0][c + 2]));
                __half2 m2 = __hfma2(gxh, gxh, __hfma2(gyh, gyh, eps2));
                __half2 mag = h2sqrt(m2);
                int gc = gx0 + j0 + c - 3;
                w.h[c] = (gc >= 0 && gc < W) ? mag : zero2;
            }
        }
        *reinterpret_cast<uint4*>(&sg[k][j0]) = w.u;
    }
    __syncthreads();

    // ---- P3: horizontal sliding 7-sums (4 output cols per task) ----
    for (int i = tid; i < 304; i += NT) {
        int k  = i >> 3;          // grad row 0..37
        int c0 = (i & 7) * 4;     // output col base 0..28
        __half2 ptv[12], sgv[12];
#pragma unroll
        for (int q = 0; q < 3; ++q) {
            U4 v; v.u = *reinterpret_cast<const uint4*>(&spt[k + 1][c0 + 4 * q]);
            ptv[4 * q] = v.h[0]; ptv[4 * q + 1] = v.h[1]; ptv[4 * q + 2] = v.h[2]; ptv[4 * q + 3] = v.h[3];
            U4 u; u.u = *reinterpret_cast<const uint4*>(&sg[k][c0 + 4 * q]);
            sgv[4 * q] = u.h[0]; sgv[4 * q + 1] = u.h[1]; sgv[4 * q + 2] = u.h[2]; sgv[4 * q + 3] = u.h[3];
        }
        __half2 gg[10], gx2[10];
#pragma unroll
        for (int q = 0; q < 10; ++q) {
            gg[q]  = __hmul2(sgv[q], sgv[q]);
            gx2[q] = __hmul2(sgv[q], h2swap(sgv[q]));
        }
        __half2 Hpt = ptv[1], Hg = sgv[0], Hgg = gg[0], Hgx = gx2[0];
#pragma unroll
        for (int q = 1; q < 7; ++q) {
            Hpt = __hadd2(Hpt, ptv[q + 1]);
            Hg  = __hadd2(Hg,  sgv[q]);
            Hgg = __hadd2(Hgg, gg[q]);
            Hgx = __hadd2(Hgx, gx2[q]);
        }
        U4 opt, og, ogg, ogx;
        opt.h[0] = Hpt; og.h[0] = Hg; ogg.h[0] = Hgg; ogx.h[0] = Hgx;
#pragma unroll
        for (int m = 1; m < 4; ++m) {
            Hpt = __hadd2(__hsub2(Hpt, ptv[m]),      ptv[m + 7]);
            Hg  = __hadd2(__hsub2(Hg,  sgv[m - 1]),  sgv[m + 6]);
            Hgg = __hadd2(__hsub2(Hgg, gg[m - 1]),   gg[m + 6]);
            Hgx = __hadd2(__hsub2(Hgx, gx2[m - 1]),  gx2[m + 6]);
            opt.h[m] = Hpt; og.h[m] = Hg; ogg.h[m] = Hgg; ogx.h[m] = Hgx;
        }
#pragma unroll
        for (int m = 0; m < 4; ++m) {
            U4 w;
            w.h[0] = opt.h[m]; w.h[1] = og.h[m]; w.h[2] = ogg.h[m]; w.h[3] = ogx.h[m];
            *reinterpret_cast<uint4*>(&hsAll[c0 + m][k][0]) = w.u;
        }
    }
    __syncthreads();

    // ---- P4: per-column vertical sliding 7-sums + SSIM ----
    float accl = 0.0f;
    {
        const int ox = tid & 31;
        const int q  = tid >> 5;     // 0..7
        const int r0 = 4 * q;        // first output row of this thread
        U4 win[10];
#pragma unroll
        for (int j = 0; j < 7; ++j)
            win[j].u = *reinterpret_cast<const uint4*>(&hsAll[ox][r0 + j][0]);
        __half2 Spt = win[0].h[0], Sg = win[0].h[1], Sgg = win[0].h[2], Sgx = win[0].h[3];
#pragma unroll
        for (int j = 1; j < 7; ++j) {
            Spt = __hadd2(Spt, win[j].h[0]);
            Sg  = __hadd2(Sg,  win[j].h[1]);
            Sgg = __hadd2(Sgg, win[j].h[2]);
            Sgx = __hadd2(Sgx, win[j].h[3]);
        }
        accl += ssim_px(Spt, Sg, Sgg, Sgx);
#pragma unroll
        for (int s = 1; s < 4; ++s) {
            win[6 + s].u = *reinterpret_cast<const uint4*>(&hsAll[ox][r0 + 6 + s][0]);
            Spt = __hadd2(__hsub2(Spt, win[s - 1].h[0]), win[6 + s].h[0]);
            Sg  = __hadd2(__hsub2(Sg,  win[s - 1].h[1]), win[6 + s].h[1]);
            Sgg = __hadd2(__hsub2(Sgg, win[s - 1].h[2]), win[6 + s].h[2]);
            Sgx = __hadd2(__hsub2(Sgx, win[s - 1].h[3]), win[6 + s].h[3]);
            accl += ssim_px(Spt, Sg, Sgg, Sgx);
        }
    }

    // ---- block reduction (deterministic) ----
#pragma unroll
    for (int off = 32; off > 0; off >>= 1) accl += __shfl_down(accl, off, 64);
    if ((tid & 63) == 0) red[tid >> 6] = accl;
    __syncthreads();
    if (tid == 0) {
        partial[((size_t)blockIdx.z * gridDim.y + blockIdx.y) * gridDim.x + blockIdx.x]
            = red[0] + red[1] + red[2] + red[3];
    }
}

__global__ __launch_bounds__(256)
void gssim_final(const float* __restrict__ partial, int n,
                 float* __restrict__ out, double inv_count) {
    __shared__ double sred[256];
    double acc = 0.0;
    for (int i = threadIdx.x; i < n; i += 256) acc += (double)partial[i];
    sred[threadIdx.x] = acc;
    __syncthreads();
    for (int s = 128; s > 0; s >>= 1) {
        if ((int)threadIdx.x < s) sred[threadIdx.x] += sred[threadIdx.x + s];
        __syncthreads();
    }
    if (threadIdx.x == 0) out[0] = (float)(1.0 - sred[0] * inv_count);
}

extern "C" void kernel_launch(void* const* d_in, const int* in_sizes, int n_in,
                              void* d_out, int out_size, void* d_ws, size_t ws_size,
                              hipStream_t stream) {
    const float* pred   = (const float*)d_in[0];
    const float* target = (const float*)d_in[1];
    const float* mn     = (const float*)d_in[2];
    const float* mx     = (const float*)d_in[3];
    float* out = (float*)d_out;

    const int B = in_sizes[2];      // 64
    const int H = 512, W = 512;

    float* partial = (float*)d_ws;

    dim3 grid(W / 32, H / 32, B);   // 16 x 16 x 64
    gssim_tile<<<grid, NT, 0, stream>>>(pred, target, mn, mx, partial, H, W);

    const int nblocks = (W / 32) * (H / 32) * B;
    const double inv_count = 1.0 / ((double)B * (double)H * (double)W);
    gssim_final<<<1, 256, 0, stream>>>(partial, nblocks, out, inv_count);
}

// Round 5
// 100.424 us; speedup vs baseline: 2.8900x; 1.0912x over previous
//
#include <hip/hip_runtime.h>
#include <hip/hip_fp16.h>
#include <math.h>

// GSSIM loss, fused tile kernel, f16-packed, conflict-free LDS layouts.
// Per 32x32 output tile:
//   P1: load+normalize (p,t) -> half2 spt[40][44]          (zero-padded halo)
//   P2: packed Sobel grad mag -> half2 sg[38][44]          (zero outside image)
//   P3: horizontal sliding 7-sums -> hsAll[col][row(41)][4] (row-consecutive lanes)
//   P4: per-column vertical sliding 7-sums + SSIM + block reduce
// Kernel 2: deterministic f64 reduce -> 1 - mean.

constexpr int NT = 256;
constexpr float EPS_F = 1e-6f;
constexpr float C1S = 2401.0f * 0.0001f;  // C1 * 49^2
constexpr float C2S = 2401.0f * 0.0009f;  // C2 * 49^2

union U4 { uint4 u; __half2 h[4]; };

// swap low/high halves of a half2 (single v_alignbit_b32)
__device__ __forceinline__ __half2 h2swap(__half2 x) {
    unsigned u = __builtin_bit_cast(unsigned, x);
    u = (u >> 16) | (u << 16);
    return __builtin_bit_cast(__half2, u);
}

__device__ __forceinline__ float ssim_px(__half2 apt, __half2 ag, __half2 agg, __half2 agx) {
    float2 vpt = __half22float2(apt);
    float2 vg  = __half22float2(ag);
    float2 vgg = __half22float2(agg);
    float  vgx = __low2float(agx);
    float lum_n = 2.0f * vpt.x * vpt.y + C1S;
    float lum_d = vpt.x * vpt.x + vpt.y * vpt.y + C1S;
    float cs_n  = 2.0f * (49.0f * vgx - vg.x * vg.y) + C2S;
    float cs_d  = 49.0f * (vgg.x + vgg.y) - vg.x * vg.x - vg.y * vg.y + C2S;
    return lum_n * cs_n * __builtin_amdgcn_rcpf(lum_d) * __builtin_amdgcn_rcpf(cs_d);
}

__global__ __launch_bounds__(NT, 4)
void gssim_tile(const float* __restrict__ pred, const float* __restrict__ target,
                const float* __restrict__ mn_arr, const float* __restrict__ mx_arr,
                float* __restrict__ partial, int H, int W) {
    __shared__ alignas(16) __half2 spt[40][44];      // (p,t); stride 44 ≡ 12 mod 32 words
    __shared__ alignas(16) __half2 sg[38][44];       // (gp,gt); stride 44
    __shared__ alignas(16) __half2 hsAll[32][41][4]; // [col][row pad 41][stat]; col stride 164 ≡ 4
    __shared__ float red[4];

    const int b   = blockIdx.z;
    const int gy0 = blockIdx.y * 32;
    const int gx0 = blockIdx.x * 32;
    const int tid = threadIdx.x;

    const float mn     = mn_arr[b];
    const float inv_dr = 1.0f / fmaxf(mx_arr[b] - mn, EPS_F);
    const size_t base  = (size_t)b * (size_t)H * (size_t)W;

    // ---- P1: load + normalize + pack (row-major lanes: global coalescing) ----
    for (int i = tid; i < 400; i += NT) {
        int y = i / 10, g = i - y * 10;
        int gy = gy0 - 4 + y;
        int gx = gx0 - 4 + 4 * g;
        U4 w;
        if (gy >= 0 && gy < H && gx >= 0 && gx + 4 <= W) {
            const float4 pv = *reinterpret_cast<const float4*>(pred   + base + (size_t)gy * W + gx);
            const float4 tv = *reinterpret_cast<const float4*>(target + base + (size_t)gy * W + gx);
            w.h[0] = __floats2half2_rn((pv.x - mn) * inv_dr, (tv.x - mn) * inv_dr);
            w.h[1] = __floats2half2_rn((pv.y - mn) * inv_dr, (tv.y - mn) * inv_dr);
            w.h[2] = __floats2half2_rn((pv.z - mn) * inv_dr, (tv.z - mn) * inv_dr);
            w.h[3] = __floats2half2_rn((pv.w - mn) * inv_dr, (tv.w - mn) * inv_dr);
        } else {
#pragma unroll
            for (int c = 0; c < 4; ++c) {
                int x = gx + c;
                bool ok = (gy >= 0 && gy < H && x >= 0 && x < W);
                float pv = 0.0f, tv = 0.0f;
                if (ok) {
                    size_t idx = base + (size_t)gy * W + (size_t)x;
                    pv = (pred[idx] - mn) * inv_dr;
                    tv = (target[idx] - mn) * inv_dr;
                }
                w.h[c] = __floats2half2_rn(pv, tv);
            }
        }
        *reinterpret_cast<uint4*>(&spt[y][4 * g]) = w.u;
    }
    __syncthreads();

    // ---- P2: packed Sobel grad magnitude ----
    const __half2 two2  = __float2half2_rn(2.0f);
    const __half2 eps2  = __float2half2_rn(1e-6f);
    const __half2 zero2 = __float2half2_rn(0.0f);
    for (int i = tid; i < 380; i += NT) {
        int k = i / 10, g = i - k * 10;
        int j0 = 4 * g;
        U4 w; w.h[0] = zero2; w.h[1] = zero2; w.h[2] = zero2; w.h[3] = zero2;
        int gr = gy0 + k - 3;
        if (gr >= 0 && gr < H) {
            __half2 a[3][6];
#pragma unroll
            for (int r = 0; r < 3; ++r) {
                U4 v; v.u = *reinterpret_cast<const uint4*>(&spt[k + r][j0]);
                a[r][0] = v.h[0]; a[r][1] = v.h[1]; a[r][2] = v.h[2]; a[r][3] = v.h[3];
                uint2 v2 = *reinterpret_cast<const uint2*>(&spt[k + r][j0 + 4]);
                a[r][4] = __builtin_bit_cast(__half2, v2.x);
                a[r][5] = __builtin_bit_cast(__half2, v2.y);
            }
#pragma unroll
            for (int c = 0; c < 4; ++c) {
                __half2 gxh = __hsub2(a[0][c + 2], a[0][c]);
                gxh = __hfma2(two2, __hsub2(a[1][c + 2], a[1][c]), gxh);
                gxh = __hadd2(gxh, __hsub2(a[2][c + 2], a[2][c]));
                __half2 gyh = __hsub2(a[2][c], a[0][c]);
                gyh = __hfma2(two2, __hsub2(a[2][c + 1], a[0][c + 1]), gyh);
                gyh = __hadd2(gyh, __hsub2(a[2][c + 2], a[0][c + 2]));
                __half2 m2 = __hfma2(gxh, gxh, __hfma2(gyh, gyh, eps2));
                __half2 mag = h2sqrt(m2);
                int gc = gx0 + j0 + c - 3;
                w.h[c] = (gc >= 0 && gc < W) ? mag : zero2;
            }
        }
        *reinterpret_cast<uint4*>(&sg[k][j0]) = w.u;
    }
    __syncthreads();

    // ---- P3: horizontal sliding 7-sums; lanes walk ROWS (conflict-free) ----
    for (int i = tid; i < 304; i += NT) {
        int cg = i / 38;          // col group 0..7
        int k  = i - cg * 38;     // grad row 0..37 (consecutive across lanes)
        int c0 = 4 * cg;          // output col base 0..28
        __half2 ptv[12], sgv[12];
#pragma unroll
        for (int q = 0; q < 3; ++q) {
            U4 v; v.u = *reinterpret_cast<const uint4*>(&spt[k + 1][c0 + 4 * q]);
            ptv[4 * q] = v.h[0]; ptv[4 * q + 1] = v.h[1]; ptv[4 * q + 2] = v.h[2]; ptv[4 * q + 3] = v.h[3];
            U4 u; u.u = *reinterpret_cast<const uint4*>(&sg[k][c0 + 4 * q]);
            sgv[4 * q] = u.h[0]; sgv[4 * q + 1] = u.h[1]; sgv[4 * q + 2] = u.h[2]; sgv[4 * q + 3] = u.h[3];
        }
        __half2 gg[10], gx2[10];
#pragma unroll
        for (int q = 0; q < 10; ++q) {
            gg[q]  = __hmul2(sgv[q], sgv[q]);
            gx2[q] = __hmul2(sgv[q], h2swap(sgv[q]));
        }
        __half2 Hpt = ptv[1], Hg = sgv[0], Hgg = gg[0], Hgx = gx2[0];
#pragma unroll
        for (int q = 1; q < 7; ++q) {
            Hpt = __hadd2(Hpt, ptv[q + 1]);
            Hg  = __hadd2(Hg,  sgv[q]);
            Hgg = __hadd2(Hgg, gg[q]);
            Hgx = __hadd2(Hgx, gx2[q]);
        }
        U4 w0;
        w0.h[0] = Hpt; w0.h[1] = Hg; w0.h[2] = Hgg; w0.h[3] = Hgx;
        *reinterpret_cast<uint4*>(&hsAll[c0][k][0]) = w0.u;
#pragma unroll
        for (int m = 1; m < 4; ++m) {
            Hpt = __hadd2(__hsub2(Hpt, ptv[m]),      ptv[m + 7]);
            Hg  = __hadd2(__hsub2(Hg,  sgv[m - 1]),  sgv[m + 6]);
            Hgg = __hadd2(__hsub2(Hgg, gg[m - 1]),   gg[m + 6]);
            Hgx = __hadd2(__hsub2(Hgx, gx2[m - 1]),  gx2[m + 6]);
            U4 w;
            w.h[0] = Hpt; w.h[1] = Hg; w.h[2] = Hgg; w.h[3] = Hgx;
            *reinterpret_cast<uint4*>(&hsAll[c0 + m][k][0]) = w.u;
        }
    }
    __syncthreads();

    // ---- P4: per-column vertical sliding 7-sums + SSIM ----
    float accl = 0.0f;
    {
        const int ox = tid & 31;
        const int q  = tid >> 5;     // 0..7
        const int r0 = 4 * q;        // first output row of this thread
        U4 win[10];
#pragma unroll
        for (int j = 0; j < 7; ++j)
            win[j].u = *reinterpret_cast<const uint4*>(&hsAll[ox][r0 + j][0]);
        __half2 Spt = win[0].h[0], Sg = win[0].h[1], Sgg = win[0].h[2], Sgx = win[0].h[3];
#pragma unroll
        for (int j = 1; j < 7; ++j) {
            Spt = __hadd2(Spt, win[j].h[0]);
            Sg  = __hadd2(Sg,  win[j].h[1]);
            Sgg = __hadd2(Sgg, win[j].h[2]);
            Sgx = __hadd2(Sgx, win[j].h[3]);
        }
        accl += ssim_px(Spt, Sg, Sgg, Sgx);
#pragma unroll
        for (int s = 1; s < 4; ++s) {
            win[6 + s].u = *reinterpret_cast<const uint4*>(&hsAll[ox][r0 + 6 + s][0]);
            Spt = __hadd2(__hsub2(Spt, win[s - 1].h[0]), win[6 + s].h[0]);
            Sg  = __hadd2(__hsub2(Sg,  win[s - 1].h[1]), win[6 + s].h[1]);
            Sgg = __hadd2(__hsub2(Sgg, win[s - 1].h[2]), win[6 + s].h[2]);
            Sgx = __hadd2(__hsub2(Sgx, win[s - 1].h[3]), win[6 + s].h[3]);
            accl += ssim_px(Spt, Sg, Sgg, Sgx);
        }
    }

    // ---- block reduction (deterministic) ----
#pragma unroll
    for (int off = 32; off > 0; off >>= 1) accl += __shfl_down(accl, off, 64);
    if ((tid & 63) == 0) red[tid >> 6] = accl;
    __syncthreads();
    if (tid == 0) {
        partial[((size_t)blockIdx.z * gridDim.y + blockIdx.y) * gridDim.x + blockIdx.x]
            = red[0] + red[1] + red[2] + red[3];
    }
}

__global__ __launch_bounds__(256)
void gssim_final(const float* __restrict__ partial, int n,
                 float* __restrict__ out, double inv_count) {
    __shared__ double sred[256];
    double acc = 0.0;
    for (int i = threadIdx.x; i < n; i += 256) acc += (double)partial[i];
    sred[threadIdx.x] = acc;
    __syncthreads();
    for (int s = 128; s > 0; s >>= 1) {
        if ((int)threadIdx.x < s) sred[threadIdx.x] += sred[threadIdx.x + s];
        __syncthreads();
    }
    if (threadIdx.x == 0) out[0] = (float)(1.0 - sred[0] * inv_count);
}

extern "C" void kernel_launch(void* const* d_in, const int* in_sizes, int n_in,
                              void* d_out, int out_size, void* d_ws, size_t ws_size,
                              hipStream_t stream) {
    const float* pred   = (const float*)d_in[0];
    const float* target = (const float*)d_in[1];
    const float* mn     = (const float*)d_in[2];
    const float* mx     = (const float*)d_in[3];
    float* out = (float*)d_out;

    const int B = in_sizes[2];      // 64
    const int H = 512, W = 512;

    float* partial = (float*)d_ws;

    dim3 grid(W / 32, H / 32, B);   // 16 x 16 x 64
    gssim_tile<<<grid, NT, 0, stream>>>(pred, target, mn, mx, partial, H, W);

    const int nblocks = (W / 32) * (H / 32) * B;
    const double inv_count = 1.0 / ((double)B * (double)H * (double)W);
    gssim_final<<<1, 256, 0, stream>>>(partial, nblocks, out, inv_count);
}

// Round 6
// 81.726 us; speedup vs baseline: 3.5513x; 1.2288x over previous
//
#include <hip/hip_runtime.h>
#include <hip/hip_fp16.h>
#include <math.h>

// GSSIM loss, persistent-strip kernel with cross-tile load pipelining.
// Each block owns a 512x32 strip (one tile row of one image), walking 16
// tiles left->right. While computing tile t (Sobel + box sums + SSIM),
// the raw float4 loads of tile t+1 are already in flight to registers.
// Per tile:
//   [A] staged regs -> normalize -> half2 spt[40][44]   (zero-padded halo)
//   [B] issue next tile's global loads -> regs
//   P2: packed Sobel grad mag -> sg[38][44]
//   P3: horizontal sliding 7-sums -> hsAll[col][41][4]
//   P4: per-column vertical sliding 7-sums + SSIM -> accl (carried)
// Kernel 2: deterministic f64 reduce -> 1 - mean.

constexpr int NT = 256;
constexpr float EPS_F = 1e-6f;
constexpr float C1S = 2401.0f * 0.0001f;  // C1 * 49^2
constexpr float C2S = 2401.0f * 0.0009f;  // C2 * 49^2

union U4 { uint4 u; __half2 h[4]; };
union F4U { float4 v; float a[4]; };

__device__ __forceinline__ __half2 h2swap(__half2 x) {
    unsigned u = __builtin_bit_cast(unsigned, x);
    u = (u >> 16) | (u << 16);
    return __builtin_bit_cast(__half2, u);
}

__device__ __forceinline__ float ssim_px(__half2 apt, __half2 ag, __half2 agg, __half2 agx) {
    float2 vpt = __half22float2(apt);
    float2 vg  = __half22float2(ag);
    float2 vgg = __half22float2(agg);
    float  vgx = __low2float(agx);
    float lum_n = 2.0f * vpt.x * vpt.y + C1S;
    float lum_d = vpt.x * vpt.x + vpt.y * vpt.y + C1S;
    float cs_n  = 2.0f * (49.0f * vgx - vg.x * vg.y) + C2S;
    float cs_d  = 49.0f * (vgg.x + vgg.y) - vg.x * vg.x - vg.y * vg.y + C2S;
    return lum_n * cs_n * __builtin_amdgcn_rcpf(lum_d) * __builtin_amdgcn_rcpf(cs_d);
}

__global__ __launch_bounds__(NT, 4)
void gssim_strip(const float* __restrict__ pred, const float* __restrict__ target,
                 const float* __restrict__ mn_arr, const float* __restrict__ mx_arr,
                 float* __restrict__ partial) {
    constexpr int H = 512, W = 512;
    __shared__ alignas(16) __half2 spt[40][44];      // (p,t); stride 44 ≡ 12 mod 32
    __shared__ alignas(16) __half2 sg[38][44];       // (gp,gt)
    __shared__ alignas(16) __half2 hsAll[32][41][4]; // [col][row pad 41][stat]
    __shared__ float red[4];

    const int blk = blockIdx.x;         // 0..1023
    const int b   = blk >> 4;           // image
    const int gy0 = (blk & 15) * 32;    // strip top row
    const int tid = threadIdx.x;

    const float mn     = mn_arr[b];
    const float inv_dr = 1.0f / fmaxf(mx_arr[b] - mn, EPS_F);
    const float* pimg = pred   + (size_t)b * H * W;
    const float* timg = target + (size_t)b * H * W;

    // fixed staging task coords (task0 = tid, task1 = tid+256 for tid<144)
    const int y0 = tid / 10, g0 = tid - y0 * 10;
    const int i1 = tid + 256;
    const int y1 = i1 / 10,  g1 = i1 - y1 * 10;
    const bool has2 = (tid < 144);
    const int gyA = gy0 - 4 + y0;
    const int gyB = gy0 - 4 + y1;
    const bool rowAok = (gyA >= 0 && gyA < H);
    const bool rowBok = (gyB >= 0 && gyB < H);

    F4U P0, T0, P1, T1;   // staged raw pixels (next tile)

    auto stage1 = [&](int gx0n, int g, bool rowok, int gyI, F4U& P, F4U& T) {
        int gx = gx0n - 4 + 4 * g;
        P.v = make_float4(0.f, 0.f, 0.f, 0.f);
        T.v = make_float4(0.f, 0.f, 0.f, 0.f);
        if (rowok) {
            if (gx >= 0 && gx + 4 <= W) {
                P.v = *reinterpret_cast<const float4*>(pimg + (size_t)gyI * W + gx);
                T.v = *reinterpret_cast<const float4*>(timg + (size_t)gyI * W + gx);
            } else {
#pragma unroll
                for (int c = 0; c < 4; ++c) {
                    int x = gx + c;
                    if (x >= 0 && x < W) {
                        P.a[c] = pimg[(size_t)gyI * W + x];
                        T.a[c] = timg[(size_t)gyI * W + x];
                    }
                }
            }
        }
    };

    auto writeA = [&](F4U& P, F4U& T, int y, int g, bool rowok, int gx0n) {
        int gx = gx0n - 4 + 4 * g;
        U4 w;
#pragma unroll
        for (int c = 0; c < 4; ++c) {
            int x = gx + c;
            bool ok = rowok && (x >= 0) && (x < W);
            float pv = ok ? (P.a[c] - mn) * inv_dr : 0.f;
            float tv = ok ? (T.a[c] - mn) * inv_dr : 0.f;
            w.h[c] = __floats2half2_rn(pv, tv);
        }
        *reinterpret_cast<uint4*>(&spt[y][4 * g]) = w.u;
    };

    // prologue: stage tile 0
    stage1(0, g0, rowAok, gyA, P0, T0);
    if (has2) stage1(0, g1, rowBok, gyB, P1, T1);

    const __half2 two2  = __float2half2_rn(2.0f);
    const __half2 eps2  = __float2half2_rn(1e-6f);
    const __half2 zero2 = __float2half2_rn(0.0f);

    float accl = 0.0f;

    for (int tx = 0; tx < 16; ++tx) {
        const int gx0 = tx * 32;

        // ---- [A] staged regs -> normalize -> spt ----
        writeA(P0, T0, y0, g0, rowAok, gx0);
        if (has2) writeA(P1, T1, y1, g1, rowBok, gx0);
        __syncthreads();

        // ---- [B] issue next tile's loads (in flight through P2..P4) ----
        if (tx < 15) {
            stage1(gx0 + 32, g0, rowAok, gyA, P0, T0);
            if (has2) stage1(gx0 + 32, g1, rowBok, gyB, P1, T1);
        }

        // ---- P2: packed Sobel grad magnitude ----
        for (int i = tid; i < 380; i += NT) {
            int k = i / 10, g = i - k * 10;
            int j0 = 4 * g;
            U4 w; w.h[0] = zero2; w.h[1] = zero2; w.h[2] = zero2; w.h[3] = zero2;
            int gr = gy0 + k - 3;
            if (gr >= 0 && gr < H) {
                __half2 a[3][6];
#pragma unroll
                for (int r = 0; r < 3; ++r) {
                    U4 v; v.u = *reinterpret_cast<const uint4*>(&spt[k + r][j0]);
                    a[r][0] = v.h[0]; a[r][1] = v.h[1]; a[r][2] = v.h[2]; a[r][3] = v.h[3];
                    uint2 v2 = *reinterpret_cast<const uint2*>(&spt[k + r][j0 + 4]);
                    a[r][4] = __builtin_bit_cast(__half2, v2.x);
                    a[r][5] = __builtin_bit_cast(__half2, v2.y);
                }
#pragma unroll
                for (int c = 0; c < 4; ++c) {
                    __half2 gxh = __hsub2(a[0][c + 2], a[0][c]);
                    gxh = __hfma2(two2, __hsub2(a[1][c + 2], a[1][c]), gxh);
                    gxh = __hadd2(gxh, __hsub2(a[2][c + 2], a[2][c]));
                    __half2 gyh = __hsub2(a[2][c], a[0][c]);
                    gyh = __hfma2(two2, __hsub2(a[2][c + 1], a[0][c + 1]), gyh);
                    gyh = __hadd2(gyh, __hsub2(a[2][c + 2], a[0][c + 2]));
                    __half2 m2 = __hfma2(gxh, gxh, __hfma2(gyh, gyh, eps2));
                    __half2 mag = h2sqrt(m2);
                    int gc = gx0 + j0 + c - 3;
                    w.h[c] = (gc >= 0 && gc < W) ? mag : zero2;
                }
            }
            *reinterpret_cast<uint4*>(&sg[k][j0]) = w.u;
        }
        __syncthreads();

        // ---- P3: horizontal sliding 7-sums (lanes walk rows) ----
        for (int i = tid; i < 304; i += NT) {
            int cg = i / 38;
            int k  = i - cg * 38;
            int c0 = 4 * cg;
            __half2 ptv[12], sgv[12];
#pragma unroll
            for (int q = 0; q < 3; ++q) {
                U4 v; v.u = *reinterpret_cast<const uint4*>(&spt[k + 1][c0 + 4 * q]);
                ptv[4 * q] = v.h[0]; ptv[4 * q + 1] = v.h[1]; ptv[4 * q + 2] = v.h[2]; ptv[4 * q + 3] = v.h[3];
                U4 u; u.u = *reinterpret_cast<const uint4*>(&sg[k][c0 + 4 * q]);
                sgv[4 * q] = u.h[0]; sgv[4 * q + 1] = u.h[1]; sgv[4 * q + 2] = u.h[2]; sgv[4 * q + 3] = u.h[3];
            }
            __half2 gg[10], gx2[10];
#pragma unroll
            for (int q = 0; q < 10; ++q) {
                gg[q]  = __hmul2(sgv[q], sgv[q]);
                gx2[q] = __hmul2(sgv[q], h2swap(sgv[q]));
            }
            __half2 Hpt = ptv[1], Hg = sgv[0], Hgg = gg[0], Hgx = gx2[0];
#pragma unroll
            for (int q = 1; q < 7; ++q) {
                Hpt = __hadd2(Hpt, ptv[q + 1]);
                Hg  = __hadd2(Hg,  sgv[q]);
                Hgg = __hadd2(Hgg, gg[q]);
                Hgx = __hadd2(Hgx, gx2[q]);
            }
            U4 w0;
            w0.h[0] = Hpt; w0.h[1] = Hg; w0.h[2] = Hgg; w0.h[3] = Hgx;
            *reinterpret_cast<uint4*>(&hsAll[c0][k][0]) = w0.u;
#pragma unroll
            for (int m = 1; m < 4; ++m) {
                Hpt = __hadd2(__hsub2(Hpt, ptv[m]),      ptv[m + 7]);
                Hg  = __hadd2(__hsub2(Hg,  sgv[m - 1]),  sgv[m + 6]);
                Hgg = __hadd2(__hsub2(Hgg, gg[m - 1]),   gg[m + 6]);
                Hgx = __hadd2(__hsub2(Hgx, gx2[m - 1]),  gx2[m + 6]);
                U4 w;
                w.h[0] = Hpt; w.h[1] = Hg; w.h[2] = Hgg; w.h[3] = Hgx;
                *reinterpret_cast<uint4*>(&hsAll[c0 + m][k][0]) = w.u;
            }
        }
        __syncthreads();

        // ---- P4: per-column vertical sliding 7-sums + SSIM ----
        {
            const int ox = tid & 31;
            const int q  = tid >> 5;
            const int r0 = 4 * q;
            U4 win[10];
#pragma unroll
            for (int j = 0; j < 7; ++j)
                win[j].u = *reinterpret_cast<const uint4*>(&hsAll[ox][r0 + j][0]);
            __half2 Spt = win[0].h[0], Sg = win[0].h[1], Sgg = win[0].h[2], Sgx = win[0].h[3];
#pragma unroll
            for (int j = 1; j < 7; ++j) {
                Spt = __hadd2(Spt, win[j].h[0]);
                Sg  = __hadd2(Sg,  win[j].h[1]);
                Sgg = __hadd2(Sgg, win[j].h[2]);
                Sgx = __hadd2(Sgx, win[j].h[3]);
            }
            accl += ssim_px(Spt, Sg, Sgg, Sgx);
#pragma unroll
            for (int s = 1; s < 4; ++s) {
                win[6 + s].u = *reinterpret_cast<const uint4*>(&hsAll[ox][r0 + 6 + s][0]);
                Spt = __hadd2(__hsub2(Spt, win[s - 1].h[0]), win[6 + s].h[0]);
                Sg  = __hadd2(__hsub2(Sg,  win[s - 1].h[1]), win[6 + s].h[1]);
                Sgg = __hadd2(__hsub2(Sgg, win[s - 1].h[2]), win[6 + s].h[2]);
                Sgx = __hadd2(__hsub2(Sgx, win[s - 1].h[3]), win[6 + s].h[3]);
                accl += ssim_px(Spt, Sg, Sgg, Sgx);
            }
        }
        __syncthreads();   // hsAll consumed; next iter's [A]/P3 may overwrite
    }

    // ---- block reduction (deterministic) ----
#pragma unroll
    for (int off = 32; off > 0; off >>= 1) accl += __shfl_down(accl, off, 64);
    if ((tid & 63) == 0) red[tid >> 6] = accl;
    __syncthreads();
    if (tid == 0) partial[blk] = red[0] + red[1] + red[2] + red[3];
}

__global__ __launch_bounds__(256)
void gssim_final(const float* __restrict__ partial, int n,
                 float* __restrict__ out, double inv_count) {
    __shared__ double sred[256];
    double acc = 0.0;
    for (int i = threadIdx.x; i < n; i += 256) acc += (double)partial[i];
    sred[threadIdx.x] = acc;
    __syncthreads();
    for (int s = 128; s > 0; s >>= 1) {
        if ((int)threadIdx.x < s) sred[threadIdx.x] += sred[threadIdx.x + s];
        __syncthreads();
    }
    if (threadIdx.x == 0) out[0] = (float)(1.0 - sred[0] * inv_count);
}

extern "C" void kernel_launch(void* const* d_in, const int* in_sizes, int n_in,
                              void* d_out, int out_size, void* d_ws, size_t ws_size,
                              hipStream_t stream) {
    const float* pred   = (const float*)d_in[0];
    const float* target = (const float*)d_in[1];
    const float* mn     = (const float*)d_in[2];
    const float* mx     = (const float*)d_in[3];
    float* out = (float*)d_out;

    const int B = in_sizes[2];      // 64
    const int H = 512, W = 512;

    float* partial = (float*)d_ws;  // 1024 floats

    const int nblocks = B * (H / 32);   // 1024 persistent strip blocks
    gssim_strip<<<nblocks, NT, 0, stream>>>(pred, target, mn, mx, partial);

    const double inv_count = 1.0 / ((double)B * (double)H * (double)W);
    gssim_final<<<1, 256, 0, stream>>>(partial, nblocks, out, inv_count);
}

// Round 7
// 79.813 us; speedup vs baseline: 3.6363x; 1.0240x over previous
//
#include <hip/hip_runtime.h>
#include <hip/hip_fp16.h>
#include <math.h>

// GSSIM loss, persistent-strip kernel, row-pair balanced phases.
// Each block owns a 512x32 strip, walking 16 tiles left->right with
// cross-tile load pipelining. Per tile (3 barriers):
//   [B] issue next tile's global loads -> regs
//   P2: packed Sobel grad mag (2 rows/task, shared loads) -> sg[38][44]
//   P3: horizontal sliding 7-sums (2 rows/task) -> hsAll[col][41][4]
//   P4: per-column vertical sliding 7-sums + SSIM -> accl (carried)
//   [A] staged regs -> normalize -> spt (next tile)
// Kernel 2: deterministic f64 reduce -> 1 - mean.

constexpr int NT = 256;
constexpr float EPS_F = 1e-6f;
constexpr float C1S = 2401.0f * 0.0001f;  // C1 * 49^2
constexpr float C2S = 2401.0f * 0.0009f;  // C2 * 49^2

union U4 { uint4 u; __half2 h[4]; };
union F4U { float4 v; float a[4]; };

__device__ __forceinline__ __half2 h2swap(__half2 x) {
    unsigned u = __builtin_bit_cast(unsigned, x);
    u = (u >> 16) | (u << 16);
    return __builtin_bit_cast(__half2, u);
}

__device__ __forceinline__ float ssim_px(__half2 apt, __half2 ag, __half2 agg, __half2 agx) {
    float2 vpt = __half22float2(apt);
    float2 vg  = __half22float2(ag);
    float2 vgg = __half22float2(agg);
    float  vgx = __low2float(agx);
    float lum_n = 2.0f * vpt.x * vpt.y + C1S;
    float lum_d = vpt.x * vpt.x + vpt.y * vpt.y + C1S;
    float cs_n  = 2.0f * (49.0f * vgx - vg.x * vg.y) + C2S;
    float cs_d  = 49.0f * (vgg.x + vgg.y) - vg.x * vg.x - vg.y * vg.y + C2S;
    return lum_n * cs_n * __builtin_amdgcn_rcpf(lum_d) * __builtin_amdgcn_rcpf(cs_d);
}

__global__ __launch_bounds__(NT, 4)
void gssim_strip(const float* __restrict__ pred, const float* __restrict__ target,
                 const float* __restrict__ mn_arr, const float* __restrict__ mx_arr,
                 float* __restrict__ partial) {
    constexpr int H = 512, W = 512;
    __shared__ alignas(16) __half2 spt[40][44];      // (p,t)
    __shared__ alignas(16) __half2 sg[38][44];       // (gp,gt)
    __shared__ alignas(16) __half2 hsAll[32][41][4]; // [col][row pad 41][stat]
    __shared__ float red[4];

    const int blk = blockIdx.x;         // 0..1023
    const int b   = blk >> 4;           // image
    const int gy0 = (blk & 15) * 32;    // strip top row
    const int tid = threadIdx.x;

    const float mn     = mn_arr[b];
    const float inv_dr = 1.0f / fmaxf(mx_arr[b] - mn, EPS_F);
    const float* pimg = pred   + (size_t)b * H * W;
    const float* timg = target + (size_t)b * H * W;

    // staging task: thread tid<200 owns input row pair (2*yr, 2*yr+1), col grp g
    const int gS  = tid % 10;
    const int yr  = tid / 10;
    const int yS0 = 2 * yr, yS1 = yS0 + 1;
    const int gyS0 = gy0 - 4 + yS0;
    const int gyS1 = gyS0 + 1;
    const bool rok0 = (gyS0 >= 0 && gyS0 < H);
    const bool rok1 = (gyS1 >= 0 && gyS1 < H);
    const bool hasS = (tid < 200);

    F4U Pa0, Ta0, Pa1, Ta1;   // staged raw pixels (next tile)

    auto stage1 = [&](int gx0n, bool rowok, int gyI, F4U& P, F4U& T) {
        int gx = gx0n - 4 + 4 * gS;
        P.v = make_float4(0.f, 0.f, 0.f, 0.f);
        T.v = make_float4(0.f, 0.f, 0.f, 0.f);
        if (rowok) {
            if (gx >= 0 && gx + 4 <= W) {
                P.v = *reinterpret_cast<const float4*>(pimg + (size_t)gyI * W + gx);
                T.v = *reinterpret_cast<const float4*>(timg + (size_t)gyI * W + gx);
            } else {
#pragma unroll
                for (int c = 0; c < 4; ++c) {
                    int x = gx + c;
                    if (x >= 0 && x < W) {
                        P.a[c] = pimg[(size_t)gyI * W + x];
                        T.a[c] = timg[(size_t)gyI * W + x];
                    }
                }
            }
        }
    };
    auto stagePair = [&](int gx0n) {
        stage1(gx0n, rok0, gyS0, Pa0, Ta0);
        stage1(gx0n, rok1, gyS1, Pa1, Ta1);
    };

    auto writeOne = [&](F4U& P, F4U& T, int y, bool rowok, int gx0n) {
        int gx = gx0n - 4 + 4 * gS;
        U4 w;
#pragma unroll
        for (int c = 0; c < 4; ++c) {
            int x = gx + c;
            bool ok = rowok && (x >= 0) && (x < W);
            float pv = ok ? (P.a[c] - mn) * inv_dr : 0.f;
            float tv = ok ? (T.a[c] - mn) * inv_dr : 0.f;
            w.h[c] = __floats2half2_rn(pv, tv);
        }
        *reinterpret_cast<uint4*>(&spt[y][4 * gS]) = w.u;
    };
    auto writePair = [&](int gx0n) {
        writeOne(Pa0, Ta0, yS0, rok0, gx0n);
        writeOne(Pa1, Ta1, yS1, rok1, gx0n);
    };

    const __half2 two2  = __float2half2_rn(2.0f);
    const __half2 eps2  = __float2half2_rn(1e-6f);
    const __half2 zero2 = __float2half2_rn(0.0f);

    // prologue: stage + write tile 0
    if (hasS) { stagePair(0); writePair(0); }
    __syncthreads();

    float accl = 0.0f;

    for (int tx = 0; tx < 16; ++tx) {
        const int gx0 = tx * 32;

        // ---- [B] issue next tile's loads (consumed after P4) ----
        if (tx < 15 && hasS) stagePair(gx0 + 32);

        // ---- P2: packed Sobel, row-pair tasks, shared spt loads ----
        if (tid < 190) {
            const int g  = tid % 10, kr = tid / 10;
            const int j0 = 4 * g, k0 = 2 * kr;
            __half2 a[4][6];
#pragma unroll
            for (int r = 0; r < 4; ++r) {
                U4 v; v.u = *reinterpret_cast<const uint4*>(&spt[k0 + r][j0]);
                a[r][0] = v.h[0]; a[r][1] = v.h[1]; a[r][2] = v.h[2]; a[r][3] = v.h[3];
                uint2 v2 = *reinterpret_cast<const uint2*>(&spt[k0 + r][j0 + 4]);
                a[r][4] = __builtin_bit_cast(__half2, v2.x);
                a[r][5] = __builtin_bit_cast(__half2, v2.y);
            }
            bool cm[4];
#pragma unroll
            for (int c = 0; c < 4; ++c) {
                int gc = gx0 + j0 + c - 3;
                cm[c] = (gc >= 0 && gc < W);
            }
#pragma unroll
            for (int rr = 0; rr < 2; ++rr) {
                const int k = k0 + rr;
                const int gr = gy0 + k - 3;
                U4 w; w.h[0] = zero2; w.h[1] = zero2; w.h[2] = zero2; w.h[3] = zero2;
                if (gr >= 0 && gr < H) {
#pragma unroll
                    for (int c = 0; c < 4; ++c) {
                        __half2 gxh = __hsub2(a[rr][c + 2], a[rr][c]);
                        gxh = __hfma2(two2, __hsub2(a[rr + 1][c + 2], a[rr + 1][c]), gxh);
                        gxh = __hadd2(gxh, __hsub2(a[rr + 2][c + 2], a[rr + 2][c]));
                        __half2 gyh = __hsub2(a[rr + 2][c], a[rr][c]);
                        gyh = __hfma2(two2, __hsub2(a[rr + 2][c + 1], a[rr][c + 1]), gyh);
                        gyh = __hadd2(gyh, __hsub2(a[rr + 2][c + 2], a[rr][c + 2]));
                        __half2 m2 = __hfma2(gxh, gxh, __hfma2(gyh, gyh, eps2));
                        __half2 mag = h2sqrt(m2);
                        w.h[c] = cm[c] ? mag : zero2;
                    }
                }
                *reinterpret_cast<uint4*>(&sg[k][j0]) = w.u;
            }
        }
        __syncthreads();

        // ---- P3: horizontal sliding 7-sums, row-pair tasks ----
        if (tid < 152) {
            const int kr = tid % 19, cg = tid / 19;
            const int c0 = 4 * cg;
#pragma unroll
            for (int rr = 0; rr < 2; ++rr) {
                const int k = 2 * kr + rr;
                __half2 ptv[12], sgv[12];
#pragma unroll
                for (int q = 0; q < 3; ++q) {
                    U4 v; v.u = *reinterpret_cast<const uint4*>(&spt[k + 1][c0 + 4 * q]);
                    ptv[4 * q] = v.h[0]; ptv[4 * q + 1] = v.h[1]; ptv[4 * q + 2] = v.h[2]; ptv[4 * q + 3] = v.h[3];
                    U4 u; u.u = *reinterpret_cast<const uint4*>(&sg[k][c0 + 4 * q]);
                    sgv[4 * q] = u.h[0]; sgv[4 * q + 1] = u.h[1]; sgv[4 * q + 2] = u.h[2]; sgv[4 * q + 3] = u.h[3];
                }
                __half2 gg[10], gx2[10];
#pragma unroll
                for (int q = 0; q < 10; ++q) {
                    gg[q]  = __hmul2(sgv[q], sgv[q]);
                    gx2[q] = __hmul2(sgv[q], h2swap(sgv[q]));
                }
                __half2 Hpt = ptv[1], Hg = sgv[0], Hgg = gg[0], Hgx = gx2[0];
#pragma unroll
                for (int q = 1; q < 7; ++q) {
                    Hpt = __hadd2(Hpt, ptv[q + 1]);
                    Hg  = __hadd2(Hg,  sgv[q]);
                    Hgg = __hadd2(Hgg, gg[q]);
                    Hgx = __hadd2(Hgx, gx2[q]);
                }
                U4 w0;
                w0.h[0] = Hpt; w0.h[1] = Hg; w0.h[2] = Hgg; w0.h[3] = Hgx;
                *reinterpret_cast<uint4*>(&hsAll[c0][k][0]) = w0.u;
#pragma unroll
                for (int m = 1; m < 4; ++m) {
                    Hpt = __hadd2(__hsub2(Hpt, ptv[m]),      ptv[m + 7]);
                    Hg  = __hadd2(__hsub2(Hg,  sgv[m - 1]),  sgv[m + 6]);
                    Hgg = __hadd2(__hsub2(Hgg, gg[m - 1]),   gg[m + 6]);
                    Hgx = __hadd2(__hsub2(Hgx, gx2[m - 1]),  gx2[m + 6]);
                    U4 w;
                    w.h[0] = Hpt; w.h[1] = Hg; w.h[2] = Hgg; w.h[3] = Hgx;
                    *reinterpret_cast<uint4*>(&hsAll[c0 + m][k][0]) = w.u;
                }
            }
        }
        __syncthreads();

        // ---- P4: per-column vertical sliding 7-sums + SSIM ----
        {
            const int ox = tid & 31;
            const int q  = tid >> 5;
            const int r0 = 4 * q;
            U4 win[10];
#pragma unroll
            for (int j = 0; j < 7; ++j)
                win[j].u = *reinterpret_cast<const uint4*>(&hsAll[ox][r0 + j][0]);
            __half2 Spt = win[0].h[0], Sg = win[0].h[1], Sgg = win[0].h[2], Sgx = win[0].h[3];
#pragma unroll
            for (int j = 1; j < 7; ++j) {
                Spt = __hadd2(Spt, win[j].h[0]);
                Sg  = __hadd2(Sg,  win[j].h[1]);
                Sgg = __hadd2(Sgg, win[j].h[2]);
                Sgx = __hadd2(Sgx, win[j].h[3]);
            }
            accl += ssim_px(Spt, Sg, Sgg, Sgx);
#pragma unroll
            for (int s = 1; s < 4; ++s) {
                win[6 + s].u = *reinterpret_cast<const uint4*>(&hsAll[ox][r0 + 6 + s][0]);
                Spt = __hadd2(__hsub2(Spt, win[s - 1].h[0]), win[6 + s].h[0]);
                Sg  = __hadd2(__hsub2(Sg,  win[s - 1].h[1]), win[6 + s].h[1]);
                Sgg = __hadd2(__hsub2(Sgg, win[s - 1].h[2]), win[6 + s].h[2]);
                Sgx = __hadd2(__hsub2(Sgx, win[s - 1].h[3]), win[6 + s].h[3]);
                accl += ssim_px(Spt, Sg, Sgg, Sgx);
            }
        }

        // ---- [A] write next tile's spt (staged loads have landed) ----
        if (tx < 15 && hasS) writePair(gx0 + 32);
        __syncthreads();
    }

    // ---- block reduction (deterministic) ----
#pragma unroll
    for (int off = 32; off > 0; off >>= 1) accl += __shfl_down(accl, off, 64);
    if ((tid & 63) == 0) red[tid >> 6] = accl;
    __syncthreads();
    if (tid == 0) partial[blk] = red[0] + red[1] + red[2] + red[3];
}

__global__ __launch_bounds__(256)
void gssim_final(const float* __restrict__ partial, int n,
                 float* __restrict__ out, double inv_count) {
    __shared__ double sred[256];
    double acc = 0.0;
    for (int i = threadIdx.x; i < n; i += 256) acc += (double)partial[i];
    sred[threadIdx.x] = acc;
    __syncthreads();
    for (int s = 128; s > 0; s >>= 1) {
        if ((int)threadIdx.x < s) sred[threadIdx.x] += sred[threadIdx.x + s];
        __syncthreads();
    }
    if (threadIdx.x == 0) out[0] = (float)(1.0 - sred[0] * inv_count);
}

extern "C" void kernel_launch(void* const* d_in, const int* in_sizes, int n_in,
                              void* d_out, int out_size, void* d_ws, size_t ws_size,
                              hipStream_t stream) {
    const float* pred   = (const float*)d_in[0];
    const float* target = (const float*)d_in[1];
    const float* mn     = (const float*)d_in[2];
    const float* mx     = (const float*)d_in[3];
    float* out = (float*)d_out;

    const int B = in_sizes[2];      // 64
    const int H = 512, W = 512;

    float* partial = (float*)d_ws;  // 1024 floats

    const int nblocks = B * (H / 32);   // 1024 persistent strip blocks
    gssim_strip<<<nblocks, NT, 0, stream>>>(pred, target, mn, mx, partial);

    const double inv_count = 1.0 / ((double)B * (double)H * (double)W);
    gssim_final<<<1, 256, 0, stream>>>(partial, nblocks, out, inv_count);
}